// Round 12
// baseline (420.929 us; speedup 1.0000x reference)
//
#include <hip/hip_runtime.h>
#include <hip/hip_bf16.h>

#define NEG_SLOPE 0.2f
#define AS 136   // padded LDS row stride (bf16 elems): breaks 128-stride bank conflicts
#define CAPD 64  // per-wave LDS ex cache depth (edges per dst); overflow -> global EX2

typedef __bf16 bf16x8 __attribute__((ext_vector_type(8)));
typedef float  f32x4  __attribute__((ext_vector_type(4)));
typedef float  f32x2  __attribute__((ext_vector_type(2)));

__device__ __forceinline__ float b2f(__hip_bfloat16 v) { return __bfloat162float(v); }
__device__ __forceinline__ __hip_bfloat16 f2b(float v) { return __float2bfloat16(v); }
__device__ __forceinline__ float lo16(unsigned u) { return __uint_as_float(u << 16); }
__device__ __forceinline__ float hi16(unsigned u) { return __uint_as_float(u & 0xFFFF0000u); }
// packed 2-channel unpack: lane's uint -> (even ch, odd ch) as f32x2
__device__ __forceinline__ f32x2 unpk2(unsigned u) {
    return (f32x2){__uint_as_float(u << 16), __uint_as_float(u & 0xFFFF0000u)};
}
__device__ __forceinline__ f32x2 max2(f32x2 a, f32x2 b) {
#if __has_builtin(__builtin_elementwise_max)
    return __builtin_elementwise_max(a, b);
#else
    return (f32x2){fmaxf(a.x, b.x), fmaxf(a.y, b.y)};
#endif
}

// wild-exponent test for one bf16-viewed ushort (even index of suspected fp32)
__device__ __forceinline__ int wild16(unsigned short w) {
    int e = (w >> 7) & 0xFF;
    return (e == 0 || e >= 0xC0) ? 1 : 0;
}

__device__ __forceinline__ void store_out(void* out, size_t idx, float v, int isF32) {
    if (isF32) ((float*)out)[idx] = v;
    else       ((__hip_bfloat16*)out)[idx] = f2b(v);
}

// ===== fused setup: weight transpose + small cvt + CNT zero (one launch) ==
#define NCVT 13
struct SetupTab {
    const void* csrc[NCVT];
    float*      cdst[NCVT];
    int         cn[NCVT];
    int         ctotal;
    const void* wsrc[5];
    __hip_bfloat16* wdst[5];
};
// block ranges: [0,nWt) weight transpose | [nWt,nWt+nZero) zero CNT | rest cvt
__global__ void k_setup(SetupTab tab, const unsigned short* __restrict__ det,
                        int* __restrict__ FLAG, int* __restrict__ CNT, int N,
                        int nWt, int nZero) {
    int b = blockIdx.x, t = threadIdx.x;
    if (b >= nWt && b < nWt + nZero) {              // CNT zeroing (no detect)
        int i = (b - nWt) * 256 + t;
        if (i < N) CNT[i] = 0;
        return;
    }
    __shared__ int sh[256];                          // block-local dtype detect
    int cnt = 0;
#pragma unroll
    for (int j = 0; j < 4; ++j) cnt += wild16(det[t * 8 + j * 2]);
    sh[t] = cnt;
    __syncthreads();
    for (int off = 128; off >= 1; off >>= 1) {
        if (t < off) sh[t] += sh[t + off];
        __syncthreads();
    }
    int isF32 = sh[0] > 128;
    if (b == 0 && t == 0) *FLAG = isF32;
    if (b < nWt) {                                   // 5x 128x128 convert+transpose
        int i = b * 256 + t;
        int m = i >> 14, rem = i & 16383, k = rem >> 7, c = rem & 127;
        float v = isF32 ? ((const float*)tab.wsrc[m])[k * 128 + c]
                        : b2f(((const __hip_bfloat16*)tab.wsrc[m])[k * 128 + c]);
        tab.wdst[m][c * 128 + k] = f2b(v);
    } else {                                         // small tensors -> f32
        int i = (b - nWt - nZero) * 256 + t;
        if (i >= tab.ctotal) return;
        int seg = 0, rem = i;
        while (rem >= tab.cn[seg]) { rem -= tab.cn[seg]; ++seg; }
        float v = isF32 ? ((const float*)tab.csrc[seg])[rem]
                        : b2f(((const __hip_bfloat16*)tab.csrc[seg])[rem]);
        tab.cdst[seg][rem] = v;
    }
}

// ---------------- CSR build (by dst), once per call -----------------------
__global__ void k_hist(const int* __restrict__ ei, int E, int N, int* __restrict__ cnt) {
    int e = blockIdx.x * blockDim.x + threadIdx.x;
    if (e >= E + N) return;
    int d = (e < E) ? ei[E + e] : (e - E);
    if ((unsigned)d >= (unsigned)N) return;
    atomicAdd(&cnt[d], 1);
}

__global__ __launch_bounds__(256) void k_scanA(const int* __restrict__ cnt, int N,
                                               int* __restrict__ rs, int* __restrict__ bsum) {
    __shared__ int sh[256];
    int t = threadIdx.x, i = blockIdx.x * 256 + t;
    int v = (i < N) ? cnt[i] : 0;
    sh[t] = v;
    __syncthreads();
    for (int off = 1; off < 256; off <<= 1) {
        int u = (t >= off) ? sh[t - off] : 0;
        __syncthreads();
        sh[t] += u;
        __syncthreads();
    }
    if (i < N) rs[i] = sh[t] - v;                    // block-local exclusive
    if (t == 255) bsum[blockIdx.x] = sh[255];
}

__global__ __launch_bounds__(1024) void k_scanB(int* __restrict__ bsum, int B,
                                                int* __restrict__ rs, int N) {
    __shared__ int sh[1024];
    int t = threadIdx.x;
    int carry = 0;
    for (int base = 0; base < B; base += 1024) {
        int idx = base + t;
        int v = (idx < B) ? bsum[idx] : 0;
        sh[t] = v;
        __syncthreads();
        for (int off = 1; off < 1024; off <<= 1) {
            int u = (t >= off) ? sh[t - off] : 0;
            __syncthreads();
            sh[t] += u;
            __syncthreads();
        }
        if (idx < B) bsum[idx] = carry + sh[t] - v;  // global exclusive
        carry += sh[1023];
        __syncthreads();
    }
    if (t == 0) rs[N] = carry;                       // total
}

__global__ __launch_bounds__(256) void k_scanC(int* __restrict__ rs, int* __restrict__ cur,
                                               const int* __restrict__ bsum, int N) {
    int i = blockIdx.x * 256 + threadIdx.x;
    if (i >= N) return;
    int v = rs[i] + bsum[blockIdx.x];
    rs[i] = v;
    cur[i] = v;
}

__global__ void k_fill(const int* __restrict__ ei, int E, int N,
                       int* __restrict__ cur, int* __restrict__ eidx,
                       int* __restrict__ srcc) {
    int e = blockIdx.x * blockDim.x + threadIdx.x;
    if (e >= E + N) return;
    int s, d;
    if (e < E) { s = ei[e]; d = ei[E + e]; } else { s = d = e - E; }
    if ((unsigned)d >= (unsigned)N) return;
    int pos = atomicAdd(&cur[d], 1);
    eidx[pos] = e;
    srcc[pos] = s;
}

// --- layer-1: fused encoder + dual MFMA GEMM ------------------------------
__global__ __launch_bounds__(256) void k_gemm2enc_mfma(
        const void* __restrict__ x, const float* __restrict__ encW,
        const float* __restrict__ encb, const int* __restrict__ flag,
        const __hip_bfloat16* __restrict__ WLt, const float* __restrict__ bl,
        const __hip_bfloat16* __restrict__ WRt, const float* __restrict__ br,
        int N, __hip_bfloat16* __restrict__ xl, __hip_bfloat16* __restrict__ xr) {
    __shared__ __hip_bfloat16 hA[64 * AS];
    __shared__ __hip_bfloat16 wB[128 * AS];
    float* encWs = (float*)wB;            // 2048 f32 (8 KB), aliased into wB
    float* xs    = encWs + 2048;          // 64*17 f32 (4.4 KB)
    int t = threadIdx.x, rbase = blockIdx.x * 64;
    int isF32 = *flag;
    for (int i = t; i < 2048; i += 256) encWs[i] = encW[i];
    for (int i = t; i < 1024; i += 256) {
        int r = i >> 4, k = i & 15, gr = rbase + r;
        float v = 0.f;
        if (gr < N)
            v = isF32 ? ((const float*)x)[(size_t)gr * 16 + k]
                      : b2f(((const __hip_bfloat16*)x)[(size_t)gr * 16 + k]);
        xs[r * 17 + k] = v;
    }
    __syncthreads();
    {   // each thread: row r = t>>2, cols c = (t&3) + cc*4  (bank-spread)
        int r = t >> 2, q = t & 3;
        float xv[16];
#pragma unroll
        for (int k = 0; k < 16; ++k) xv[k] = xs[r * 17 + k];
#pragma unroll
        for (int cc = 0; cc < 32; ++cc) {
            int c = q + cc * 4;
            float acc = encb[c];
#pragma unroll
            for (int k = 0; k < 16; ++k) acc += xv[k] * encWs[k * 128 + c];
            hA[r * AS + c] = f2b(acc);
        }
    }
    int wave = t >> 6, lane = t & 63, l16 = lane & 15, kq = lane >> 4;
#pragma unroll
    for (int pass = 0; pass < 2; ++pass) {
        const __hip_bfloat16* Wt = pass ? WRt : WLt;
        const float* bias        = pass ? br  : bl;
        __hip_bfloat16* out      = pass ? xr  : xl;
        __syncthreads();                           // hA done / wB free
        for (int i = t; i < 2048; i += 256) {      // stage Wt (32 KB)
            int c = i >> 4, seg = i & 15;
            ((uint4*)(wB + c * AS))[seg] = ((const uint4*)(Wt + c * 128))[seg];
        }
        __syncthreads();
        f32x4 acc[8];
#pragma unroll
        for (int i = 0; i < 8; ++i) acc[i] = (f32x4){0.f, 0.f, 0.f, 0.f};
#pragma unroll
        for (int ks = 0; ks < 4; ++ks) {
            int kofs = ks * 32 + kq * 8;
            bf16x8 a = *(const bf16x8*)(hA + (wave * 16 + l16) * AS + kofs);
#pragma unroll
            for (int cb = 0; cb < 8; ++cb) {
                bf16x8 b = *(const bf16x8*)(wB + (cb * 16 + l16) * AS + kofs);
                acc[cb] = __builtin_amdgcn_mfma_f32_16x16x32_bf16(a, b, acc[cb], 0, 0, 0);
            }
        }
#pragma unroll
        for (int cb = 0; cb < 8; ++cb) {
            int c = cb * 16 + l16;
            float bc = bias[c];
#pragma unroll
            for (int i = 0; i < 4; ++i) {
                int r = rbase + wave * 16 + kq * 4 + i;
                if (r < N) out[(size_t)r * 128 + c] = f2b(acc[cb][i] + bc);
            }
        }
    }
}

// --- dual MFMA GEMM: stage hA once, loop over {Wl->xl, Wr->xr} -------------
__global__ __launch_bounds__(256) void k_gemm2_mfma(
        const __hip_bfloat16* __restrict__ in,
        const __hip_bfloat16* __restrict__ WLt, const float* __restrict__ bl,
        const __hip_bfloat16* __restrict__ WRt, const float* __restrict__ br,
        int N, __hip_bfloat16* __restrict__ xl, __hip_bfloat16* __restrict__ xr) {
    __shared__ __hip_bfloat16 hA[64 * AS];
    __shared__ __hip_bfloat16 wB[128 * AS];
    int t = threadIdx.x, rbase = blockIdx.x * 64;
    for (int i = t; i < 1024; i += 256) {          // stage 64 h rows (16 KB) ONCE
        int r = i >> 4, seg = i & 15;
        int gr = rbase + r;
        uint4 v = {0u, 0u, 0u, 0u};
        if (gr < N) v = ((const uint4*)(in + (size_t)gr * 128))[seg];
        ((uint4*)(hA + r * AS))[seg] = v;
    }
    int wave = t >> 6, lane = t & 63, l16 = lane & 15, kq = lane >> 4;
#pragma unroll
    for (int pass = 0; pass < 2; ++pass) {
        const __hip_bfloat16* Wt = pass ? WRt : WLt;
        const float* bias        = pass ? br  : bl;
        __hip_bfloat16* out      = pass ? xr  : xl;
        __syncthreads();
        for (int i = t; i < 2048; i += 256) {      // stage Wt (32 KB)
            int c = i >> 4, seg = i & 15;
            ((uint4*)(wB + c * AS))[seg] = ((const uint4*)(Wt + c * 128))[seg];
        }
        __syncthreads();
        f32x4 acc[8];
#pragma unroll
        for (int i = 0; i < 8; ++i) acc[i] = (f32x4){0.f, 0.f, 0.f, 0.f};
#pragma unroll
        for (int ks = 0; ks < 4; ++ks) {
            int kofs = ks * 32 + kq * 8;
            bf16x8 a = *(const bf16x8*)(hA + (wave * 16 + l16) * AS + kofs);
#pragma unroll
            for (int cb = 0; cb < 8; ++cb) {
                bf16x8 b = *(const bf16x8*)(wB + (cb * 16 + l16) * AS + kofs);
                acc[cb] = __builtin_amdgcn_mfma_f32_16x16x32_bf16(a, b, acc[cb], 0, 0, 0);
            }
        }
#pragma unroll
        for (int cb = 0; cb < 8; ++cb) {
            int c = cb * 16 + l16;
            float bc = bias[c];
#pragma unroll
            for (int i = 0; i < 4; ++i) {
                int r = rbase + wave * 16 + kq * 4 + i;
                if (r < N) out[(size_t)r * 128 + c] = f2b(acc[cb][i] + bc);
            }
        }
    }
}

// --------- MFMA MLP head: sigmoid(relu(h2@W1+b1)@W2 + b2), fused ----------
__global__ __launch_bounds__(256) void k_mlp_mfma(
        const __hip_bfloat16* __restrict__ h2, const __hip_bfloat16* __restrict__ W1t,
        const float* __restrict__ b1, const float* __restrict__ W2,
        const float* __restrict__ b2, int N,
        void* __restrict__ d_out, const int* __restrict__ flag) {
    __shared__ __hip_bfloat16 hA[64 * AS];
    __shared__ __hip_bfloat16 wB[128 * AS];
    int t = threadIdx.x, rbase = blockIdx.x * 64;
    for (int i = t; i < 2048; i += 256) {
        int c = i >> 4, seg = i & 15;
        ((uint4*)(wB + c * AS))[seg] = ((const uint4*)(W1t + c * 128))[seg];
    }
    for (int i = t; i < 1024; i += 256) {
        int r = i >> 4, seg = i & 15;
        int gr = rbase + r;
        uint4 v = {0u, 0u, 0u, 0u};
        if (gr < N) v = ((const uint4*)(h2 + (size_t)gr * 128))[seg];
        ((uint4*)(hA + r * AS))[seg] = v;
    }
    __syncthreads();
    int wave = t >> 6, lane = t & 63, l16 = lane & 15, kq = lane >> 4;
    f32x4 acc[8];
#pragma unroll
    for (int i = 0; i < 8; ++i) acc[i] = (f32x4){0.f, 0.f, 0.f, 0.f};
#pragma unroll
    for (int ks = 0; ks < 4; ++ks) {
        int kofs = ks * 32 + kq * 8;
        bf16x8 a = *(const bf16x8*)(hA + (wave * 16 + l16) * AS + kofs);
#pragma unroll
        for (int cb = 0; cb < 8; ++cb) {
            bf16x8 b = *(const bf16x8*)(wB + (cb * 16 + l16) * AS + kofs);
            acc[cb] = __builtin_amdgcn_mfma_f32_16x16x32_bf16(a, b, acc[cb], 0, 0, 0);
        }
    }
    float p[4] = {0.f, 0.f, 0.f, 0.f};
#pragma unroll
    for (int cb = 0; cb < 8; ++cb) {
        int c = cb * 16 + l16;
        float bb = b1[c], w = W2[c];
#pragma unroll
        for (int i = 0; i < 4; ++i) p[i] += fmaxf(acc[cb][i] + bb, 0.f) * w;
    }
#pragma unroll
    for (int i = 0; i < 4; ++i) {
        p[i] += __shfl_xor(p[i], 8, 16);
        p[i] += __shfl_xor(p[i], 4, 16);
        p[i] += __shfl_xor(p[i], 2, 16);
        p[i] += __shfl_xor(p[i], 1, 16);
    }
    if (l16 == 0) {
        int isF32 = *flag;
        float bb = b2[0];
#pragma unroll
        for (int i = 0; i < 4; ++i) {
            int r = rbase + wave * 16 + kq * 4 + i;
            if (r < N)
                store_out(d_out, (size_t)r,
                          1.f / (1.f + __expf(-(p[i] + bb))), isF32);
        }
    }
}

// ===== fused GAT edge pipeline: packed f32x2 math, 8-way, LDS ex cache ====
__global__ __launch_bounds__(256) void k_gat_fused(
        const __hip_bfloat16* __restrict__ xl,
        const __hip_bfloat16* __restrict__ xr,
        const int* __restrict__ rs, const int* __restrict__ srcc,
        const int* __restrict__ eidx, int N,
        const float* __restrict__ att, const float* __restrict__ bo, int relu,
        float* __restrict__ EX2,
        void* __restrict__ alpha_out, size_t aoff, const int* __restrict__ flag,
        __hip_bfloat16* __restrict__ hout) {
    __shared__ float exsh[4][CAPD * 4];     // per-wave ex cache (4 KB)
    int wv = threadIdx.x >> 6, lane = threadIdx.x & 63;
    int n = blockIdx.x * 4 + wv;
    if (n >= N) return;
    int h = lane >> 4, l16 = lane & 15, c0 = lane * 2;
    f32x2 xr2 = unpk2(((const unsigned*)(xr + (size_t)n * 128))[lane]);
    f32x2 a2  = *(const f32x2*)(att + c0);
    int beg = rs[n], end = rs[n + 1];
    float den = 0.f;
    f32x2 acc2 = (f32x2){0.f, 0.f};
    int r = beg;
    for (; r + 8 <= end; r += 8) {                 // 8 independent edges in flight
        f32x2 xv[8];
#pragma unroll
        for (int j = 0; j < 8; ++j) {
            unsigned s = min((unsigned)srcc[r + j], (unsigned)(N - 1));
            xv[j] = unpk2(((const unsigned*)(xl + (size_t)s * 128))[lane]);
        }
        float p[8];
#pragma unroll
        for (int j = 0; j < 8; ++j) {
            f32x2 v = xv[j] + xr2;
            v = max2(v, v * NEG_SLOPE);            // leaky (packed)
            f32x2 m = v * a2;
            p[j] = m.x + m.y;
        }
#pragma unroll
        for (int st = 1; st < 16; st <<= 1) {
#pragma unroll
            for (int j = 0; j < 8; ++j) p[j] += __shfl_xor(p[j], st, 16);
        }
        float ex[8];
#pragma unroll
        for (int j = 0; j < 8; ++j) ex[j] = __expf(fminf(fmaxf(p[j], -30.f), 30.f));
        if (l16 == 0) {
#pragma unroll
            for (int j = 0; j < 8; ++j) {
                int idx = r + j - beg;
                if (idx < CAPD) exsh[wv][idx * 4 + h] = ex[j];
                else            EX2[(size_t)(r + j) * 4 + h] = ex[j];
            }
        }
#pragma unroll
        for (int j = 0; j < 8; ++j) {
            den  += ex[j];
            acc2 += xv[j] * ex[j];                 // packed fma
        }
    }
    if (r < end) {                                 // masked tail (1..7 edges)
        f32x2 xv[8];
#pragma unroll
        for (int j = 0; j < 8; ++j) {
            int rr = (r + j < end) ? (r + j) : (end - 1);
            unsigned s = min((unsigned)srcc[rr], (unsigned)(N - 1));
            xv[j] = unpk2(((const unsigned*)(xl + (size_t)s * 128))[lane]);
        }
        float p[8];
#pragma unroll
        for (int j = 0; j < 8; ++j) {
            f32x2 v = xv[j] + xr2;
            v = max2(v, v * NEG_SLOPE);
            f32x2 m = v * a2;
            p[j] = m.x + m.y;
        }
#pragma unroll
        for (int st = 1; st < 16; st <<= 1) {
#pragma unroll
            for (int j = 0; j < 8; ++j) p[j] += __shfl_xor(p[j], st, 16);
        }
        float ex[8];
#pragma unroll
        for (int j = 0; j < 8; ++j)
            ex[j] = (r + j < end) ? __expf(fminf(fmaxf(p[j], -30.f), 30.f)) : 0.f;
        if (l16 == 0) {
#pragma unroll
            for (int j = 0; j < 8; ++j) {
                if (r + j < end) {
                    int idx = r + j - beg;
                    if (idx < CAPD) exsh[wv][idx * 4 + h] = ex[j];
                    else            EX2[(size_t)(r + j) * 4 + h] = ex[j];
                }
            }
        }
#pragma unroll
        for (int j = 0; j < 8; ++j) {
            den  += ex[j];
            acc2 += xv[j] * ex[j];
        }
    }
    float invn = 1.f / fmaxf(den, 1e-30f);
    f32x2 bo2 = *(const f32x2*)(bo + c0);
    f32x2 o = acc2 * invn + bo2;
    if (relu) o = max2(o, (f32x2){0.f, 0.f});
    __hip_bfloat16 h0 = f2b(o.x), h1 = f2b(o.y);
    ushort2 st;
    st.x = *(unsigned short*)&h0;
    st.y = *(unsigned short*)&h1;
    ((ushort2*)(hout + (size_t)n * 128))[lane] = st;
    // alpha outputs: 16 edges in parallel, lane (h,l16) handles (r0+l16, h)
    int isF32 = *flag;
    for (int r0 = beg; r0 < end; r0 += 16) {
        int rr = r0 + l16;
        if (rr < end) {
            int idx = rr - beg;
            float ex = (idx < CAPD) ? exsh[wv][idx * 4 + h]
                                    : EX2[(size_t)rr * 4 + h];
            int e = eidx[rr];
            store_out(alpha_out, aoff + (size_t)e * 4 + h, ex * invn, isF32);
        }
    }
}

extern "C" void kernel_launch(void* const* d_in, const int* in_sizes, int n_in,
                              void* d_out, int out_size, void* d_ws, size_t ws_size,
                              hipStream_t stream) {
    const int* ei = (const int*)d_in[1];
    const int N  = in_sizes[0] / 16;
    const int E  = in_sizes[1] / 2;
    const int ET = E + N;
    const int NB = (N + 255) / 256;          // scan blocks

    // ---------------- workspace carve ------------------------------------
    float* P = (float*)d_ws;
    float* encW = P; P += 2048;  float* encb = P; P += 128;
    float* b1l  = P; P += 128;   float* b1r  = P; P += 128;
    float* att1 = P; P += 128;   float* bo1  = P; P += 128;
    float* b2l  = P; P += 128;   float* b2r  = P; P += 128;
    float* att2 = P; P += 128;   float* bo2  = P; P += 128;
    float* mb1  = P; P += 128;   float* mW2  = P; P += 128;
    float* mb2  = P; P += 4;
    int*  FLAG  = (int*)P; P += 4;
    int*  CNT   = (int*)P; P += N;
    int*  RS    = (int*)P; P += N + 1;
    int*  CUR   = (int*)P; P += N;
    int*  BSUM  = (int*)P; P += NB;
    int*  EIDX  = (int*)P; P += ET;
    int*  SRC   = (int*)P; P += ET;
    float* EX2  = P; P += (size_t)ET * 4;
    P = (float*)(((uintptr_t)P + 15) & ~(uintptr_t)15);   // 16B align
    __hip_bfloat16* W1Lt = (__hip_bfloat16*)P;            // 5 x 128*128 bf16
    __hip_bfloat16* W1Rt = W1Lt + 16384;
    __hip_bfloat16* W2Lt = W1Rt + 16384;
    __hip_bfloat16* W2Rt = W2Lt + 16384;
    __hip_bfloat16* MW1t = W2Rt + 16384;
    __hip_bfloat16* Hb   = MW1t + 16384;                  // N*128 bf16
    __hip_bfloat16* XL   = Hb + (size_t)N * 128;
    __hip_bfloat16* XR   = XL + (size_t)N * 128;

    // ---------------- fused setup (cvt + transpose + CNT zero) ------------
    SetupTab tab;
    const int srcIdx[NCVT] = {4, 5, 7, 9, 10, 11, 13, 15, 16, 17, 19, 20, 21};
    float* dsts[NCVT] = {encW, encb, b1l, b1r, att1, bo1, b2l, b2r, att2, bo2, mb1, mW2, mb2};
    const int ns[NCVT] = {2048, 128, 128, 128, 128, 128, 128, 128, 128, 128, 128, 128, 1};
    int tot = 0;
    for (int i = 0; i < NCVT; ++i) {
        tab.csrc[i] = d_in[srcIdx[i]];
        tab.cdst[i] = dsts[i];
        tab.cn[i] = ns[i];
        tot += ns[i];
    }
    tab.ctotal = tot;
    tab.wsrc[0] = d_in[6];  tab.wdst[0] = W1Lt;
    tab.wsrc[1] = d_in[8];  tab.wdst[1] = W1Rt;
    tab.wsrc[2] = d_in[12]; tab.wdst[2] = W2Lt;
    tab.wsrc[3] = d_in[14]; tab.wdst[3] = W2Rt;
    tab.wsrc[4] = d_in[18]; tab.wdst[4] = MW1t;
    const unsigned short* det = (const unsigned short*)d_in[4];  // enc_W raw
    const int nWt   = 5 * 16384 / 256;     // 320
    const int nCvt  = (tot + 255) / 256;
    k_setup<<<nWt + NB + nCvt, 256, 0, stream>>>(tab, det, FLAG, CNT, N, nWt, NB);

    // ---------------- CSR by dst (parallel scan) --------------------------
    const int etGrid = (ET + 255) / 256;
    k_hist<<<etGrid, 256, 0, stream>>>(ei, E, N, CNT);
    k_scanA<<<NB, 256, 0, stream>>>(CNT, N, RS, BSUM);
    k_scanB<<<1, 1024, 0, stream>>>(BSUM, NB, RS, N);
    k_scanC<<<NB, 256, 0, stream>>>(RS, CUR, BSUM, N);
    k_fill<<<etGrid, 256, 0, stream>>>(ei, E, N, CUR, EIDX, SRC);

    const size_t a1_off = (size_t)N;
    const size_t a2_off = (size_t)N + (size_t)ET * 4;
    const int gGrid = (N + 63) / 64;
    const int fGrid = (N + 3) / 4;

    // ---- GAT layer 1 (encoder fused into the GEMM) ----
    k_gemm2enc_mfma<<<gGrid, 256, 0, stream>>>(d_in[0], encW, encb, FLAG,
                                               W1Lt, b1l, W1Rt, b1r, N, XL, XR);
    k_gat_fused<<<fGrid, 256, 0, stream>>>(XL, XR, RS, SRC, EIDX, N, att1, bo1, 1,
                                           EX2, d_out, a1_off, FLAG, Hb);

    // ---- GAT layer 2 ----
    k_gemm2_mfma<<<gGrid, 256, 0, stream>>>(Hb, W2Lt, b2l, W2Rt, b2r, N, XL, XR);
    k_gat_fused<<<fGrid, 256, 0, stream>>>(XL, XR, RS, SRC, EIDX, N, att2, bo2, 0,
                                           EX2, d_out, a2_off, FLAG, Hb);

    k_mlp_mfma<<<gGrid, 256, 0, stream>>>(Hb, MW1t, mb1, mW2, mb2, N, d_out, FLAG);
}

// Round 13
// 415.766 us; speedup vs baseline: 1.0124x; 1.0124x over previous
//
#include <hip/hip_runtime.h>
#include <hip/hip_bf16.h>

#define NEG_SLOPE 0.2f
#define AS 136   // padded LDS row stride (bf16 elems): breaks 128-stride bank conflicts
#define CAPD 64  // per-wave LDS ex cache depth (edges per dst); overflow -> global EX2

typedef __bf16 bf16x8 __attribute__((ext_vector_type(8)));
typedef float  f32x4  __attribute__((ext_vector_type(4)));

__device__ __forceinline__ float b2f(__hip_bfloat16 v) { return __bfloat162float(v); }
__device__ __forceinline__ __hip_bfloat16 f2b(float v) { return __float2bfloat16(v); }
__device__ __forceinline__ float lo16(unsigned u) { return __uint_as_float(u << 16); }
__device__ __forceinline__ float hi16(unsigned u) { return __uint_as_float(u & 0xFFFF0000u); }

// wild-exponent test for one bf16-viewed ushort (even index of suspected fp32)
__device__ __forceinline__ int wild16(unsigned short w) {
    int e = (w >> 7) & 0xFF;
    return (e == 0 || e >= 0xC0) ? 1 : 0;
}

__device__ __forceinline__ void store_out(void* out, size_t idx, float v, int isF32) {
    if (isF32) ((float*)out)[idx] = v;
    else       ((__hip_bfloat16*)out)[idx] = f2b(v);
}

// ===== fused setup: weight transpose + small cvt + CNT zero (one launch) ==
#define NCVT 13
struct SetupTab {
    const void* csrc[NCVT];
    float*      cdst[NCVT];
    int         cn[NCVT];
    int         ctotal;
    const void* wsrc[5];
    __hip_bfloat16* wdst[5];
};
// block ranges: [0,nWt) weight transpose | [nWt,nWt+nZero) zero CNT | rest cvt
__global__ void k_setup(SetupTab tab, const unsigned short* __restrict__ det,
                        int* __restrict__ FLAG, int* __restrict__ CNT, int N,
                        int nWt, int nZero) {
    int b = blockIdx.x, t = threadIdx.x;
    if (b >= nWt && b < nWt + nZero) {              // CNT zeroing (no detect)
        int i = (b - nWt) * 256 + t;
        if (i < N) CNT[i] = 0;
        return;
    }
    __shared__ int sh[256];                          // block-local dtype detect
    int cnt = 0;
#pragma unroll
    for (int j = 0; j < 4; ++j) cnt += wild16(det[t * 8 + j * 2]);
    sh[t] = cnt;
    __syncthreads();
    for (int off = 128; off >= 1; off >>= 1) {
        if (t < off) sh[t] += sh[t + off];
        __syncthreads();
    }
    int isF32 = sh[0] > 128;
    if (b == 0 && t == 0) *FLAG = isF32;
    if (b < nWt) {                                   // 5x 128x128 convert+transpose
        int i = b * 256 + t;
        int m = i >> 14, rem = i & 16383, k = rem >> 7, c = rem & 127;
        float v = isF32 ? ((const float*)tab.wsrc[m])[k * 128 + c]
                        : b2f(((const __hip_bfloat16*)tab.wsrc[m])[k * 128 + c]);
        tab.wdst[m][c * 128 + k] = f2b(v);
    } else {                                         // small tensors -> f32
        int i = (b - nWt - nZero) * 256 + t;
        if (i >= tab.ctotal) return;
        int seg = 0, rem = i;
        while (rem >= tab.cn[seg]) { rem -= tab.cn[seg]; ++seg; }
        float v = isF32 ? ((const float*)tab.csrc[seg])[rem]
                        : b2f(((const __hip_bfloat16*)tab.csrc[seg])[rem]);
        tab.cdst[seg][rem] = v;
    }
}

// ---------------- CSR build (by dst), once per call -----------------------
__global__ void k_hist(const int* __restrict__ ei, int E, int N, int* __restrict__ cnt) {
    int e = blockIdx.x * blockDim.x + threadIdx.x;
    if (e >= E + N) return;
    int d = (e < E) ? ei[E + e] : (e - E);
    if ((unsigned)d >= (unsigned)N) return;
    atomicAdd(&cnt[d], 1);
}

// scanA pads each row's count to a multiple of 4 -> every row start is
// 16B-aligned in EIDX/SRC (int4-loadable). True degree stays in CNT.
__global__ __launch_bounds__(256) void k_scanA(const int* __restrict__ cnt, int N,
                                               int* __restrict__ rs, int* __restrict__ bsum) {
    __shared__ int sh[256];
    int t = threadIdx.x, i = blockIdx.x * 256 + t;
    int v = (i < N) ? ((cnt[i] + 3) & ~3) : 0;       // padded count
    sh[t] = v;
    __syncthreads();
    for (int off = 1; off < 256; off <<= 1) {
        int u = (t >= off) ? sh[t - off] : 0;
        __syncthreads();
        sh[t] += u;
        __syncthreads();
    }
    if (i < N) rs[i] = sh[t] - v;                    // block-local exclusive
    if (t == 255) bsum[blockIdx.x] = sh[255];
}

__global__ __launch_bounds__(1024) void k_scanB(int* __restrict__ bsum, int B,
                                                int* __restrict__ rs, int N) {
    __shared__ int sh[1024];
    int t = threadIdx.x;
    int carry = 0;
    for (int base = 0; base < B; base += 1024) {
        int idx = base + t;
        int v = (idx < B) ? bsum[idx] : 0;
        sh[t] = v;
        __syncthreads();
        for (int off = 1; off < 1024; off <<= 1) {
            int u = (t >= off) ? sh[t - off] : 0;
            __syncthreads();
            sh[t] += u;
            __syncthreads();
        }
        if (idx < B) bsum[idx] = carry + sh[t] - v;  // global exclusive
        carry += sh[1023];
        __syncthreads();
    }
    if (t == 0) rs[N] = carry;                       // padded total
}

__global__ __launch_bounds__(256) void k_scanC(int* __restrict__ rs, int* __restrict__ cur,
                                               const int* __restrict__ bsum, int N) {
    int i = blockIdx.x * 256 + threadIdx.x;
    if (i >= N) return;
    int v = rs[i] + bsum[blockIdx.x];
    rs[i] = v;
    cur[i] = v;
}

__global__ void k_fill(const int* __restrict__ ei, int E, int N,
                       int* __restrict__ cur, int* __restrict__ eidx,
                       int* __restrict__ srcc) {
    int e = blockIdx.x * blockDim.x + threadIdx.x;
    if (e >= E + N) return;
    int s, d;
    if (e < E) { s = ei[e]; d = ei[E + e]; } else { s = d = e - E; }
    if ((unsigned)d >= (unsigned)N) return;
    int pos = atomicAdd(&cur[d], 1);
    eidx[pos] = e;
    srcc[pos] = s;
}

// --- layer-1: fused encoder + dual MFMA GEMM ------------------------------
__global__ __launch_bounds__(256) void k_gemm2enc_mfma(
        const void* __restrict__ x, const float* __restrict__ encW,
        const float* __restrict__ encb, const int* __restrict__ flag,
        const __hip_bfloat16* __restrict__ WLt, const float* __restrict__ bl,
        const __hip_bfloat16* __restrict__ WRt, const float* __restrict__ br,
        int N, __hip_bfloat16* __restrict__ xl, __hip_bfloat16* __restrict__ xr) {
    __shared__ __hip_bfloat16 hA[64 * AS];
    __shared__ __hip_bfloat16 wB[128 * AS];
    float* encWs = (float*)wB;            // 2048 f32 (8 KB), aliased into wB
    float* xs    = encWs + 2048;          // 64*17 f32 (4.4 KB)
    int t = threadIdx.x, rbase = blockIdx.x * 64;
    int isF32 = *flag;
    for (int i = t; i < 2048; i += 256) encWs[i] = encW[i];
    for (int i = t; i < 1024; i += 256) {
        int r = i >> 4, k = i & 15, gr = rbase + r;
        float v = 0.f;
        if (gr < N)
            v = isF32 ? ((const float*)x)[(size_t)gr * 16 + k]
                      : b2f(((const __hip_bfloat16*)x)[(size_t)gr * 16 + k]);
        xs[r * 17 + k] = v;
    }
    __syncthreads();
    {   // each thread: row r = t>>2, cols c = (t&3) + cc*4  (bank-spread)
        int r = t >> 2, q = t & 3;
        float xv[16];
#pragma unroll
        for (int k = 0; k < 16; ++k) xv[k] = xs[r * 17 + k];
#pragma unroll
        for (int cc = 0; cc < 32; ++cc) {
            int c = q + cc * 4;
            float acc = encb[c];
#pragma unroll
            for (int k = 0; k < 16; ++k) acc += xv[k] * encWs[k * 128 + c];
            hA[r * AS + c] = f2b(acc);
        }
    }
    int wave = t >> 6, lane = t & 63, l16 = lane & 15, kq = lane >> 4;
#pragma unroll
    for (int pass = 0; pass < 2; ++pass) {
        const __hip_bfloat16* Wt = pass ? WRt : WLt;
        const float* bias        = pass ? br  : bl;
        __hip_bfloat16* out      = pass ? xr  : xl;
        __syncthreads();                           // hA done / wB free
        for (int i = t; i < 2048; i += 256) {      // stage Wt (32 KB)
            int c = i >> 4, seg = i & 15;
            ((uint4*)(wB + c * AS))[seg] = ((const uint4*)(Wt + c * 128))[seg];
        }
        __syncthreads();
        f32x4 acc[8];
#pragma unroll
        for (int i = 0; i < 8; ++i) acc[i] = (f32x4){0.f, 0.f, 0.f, 0.f};
#pragma unroll
        for (int ks = 0; ks < 4; ++ks) {
            int kofs = ks * 32 + kq * 8;
            bf16x8 a = *(const bf16x8*)(hA + (wave * 16 + l16) * AS + kofs);
#pragma unroll
            for (int cb = 0; cb < 8; ++cb) {
                bf16x8 b = *(const bf16x8*)(wB + (cb * 16 + l16) * AS + kofs);
                acc[cb] = __builtin_amdgcn_mfma_f32_16x16x32_bf16(a, b, acc[cb], 0, 0, 0);
            }
        }
#pragma unroll
        for (int cb = 0; cb < 8; ++cb) {
            int c = cb * 16 + l16;
            float bc = bias[c];
#pragma unroll
            for (int i = 0; i < 4; ++i) {
                int r = rbase + wave * 16 + kq * 4 + i;
                if (r < N) out[(size_t)r * 128 + c] = f2b(acc[cb][i] + bc);
            }
        }
    }
}

// --- dual MFMA GEMM: stage hA once, loop over {Wl->xl, Wr->xr} -------------
__global__ __launch_bounds__(256) void k_gemm2_mfma(
        const __hip_bfloat16* __restrict__ in,
        const __hip_bfloat16* __restrict__ WLt, const float* __restrict__ bl,
        const __hip_bfloat16* __restrict__ WRt, const float* __restrict__ br,
        int N, __hip_bfloat16* __restrict__ xl, __hip_bfloat16* __restrict__ xr) {
    __shared__ __hip_bfloat16 hA[64 * AS];
    __shared__ __hip_bfloat16 wB[128 * AS];
    int t = threadIdx.x, rbase = blockIdx.x * 64;
    for (int i = t; i < 1024; i += 256) {          // stage 64 h rows (16 KB) ONCE
        int r = i >> 4, seg = i & 15;
        int gr = rbase + r;
        uint4 v = {0u, 0u, 0u, 0u};
        if (gr < N) v = ((const uint4*)(in + (size_t)gr * 128))[seg];
        ((uint4*)(hA + r * AS))[seg] = v;
    }
    int wave = t >> 6, lane = t & 63, l16 = lane & 15, kq = lane >> 4;
#pragma unroll
    for (int pass = 0; pass < 2; ++pass) {
        const __hip_bfloat16* Wt = pass ? WRt : WLt;
        const float* bias        = pass ? br  : bl;
        __hip_bfloat16* out      = pass ? xr  : xl;
        __syncthreads();
        for (int i = t; i < 2048; i += 256) {      // stage Wt (32 KB)
            int c = i >> 4, seg = i & 15;
            ((uint4*)(wB + c * AS))[seg] = ((const uint4*)(Wt + c * 128))[seg];
        }
        __syncthreads();
        f32x4 acc[8];
#pragma unroll
        for (int i = 0; i < 8; ++i) acc[i] = (f32x4){0.f, 0.f, 0.f, 0.f};
#pragma unroll
        for (int ks = 0; ks < 4; ++ks) {
            int kofs = ks * 32 + kq * 8;
            bf16x8 a = *(const bf16x8*)(hA + (wave * 16 + l16) * AS + kofs);
#pragma unroll
            for (int cb = 0; cb < 8; ++cb) {
                bf16x8 b = *(const bf16x8*)(wB + (cb * 16 + l16) * AS + kofs);
                acc[cb] = __builtin_amdgcn_mfma_f32_16x16x32_bf16(a, b, acc[cb], 0, 0, 0);
            }
        }
#pragma unroll
        for (int cb = 0; cb < 8; ++cb) {
            int c = cb * 16 + l16;
            float bc = bias[c];
#pragma unroll
            for (int i = 0; i < 4; ++i) {
                int r = rbase + wave * 16 + kq * 4 + i;
                if (r < N) out[(size_t)r * 128 + c] = f2b(acc[cb][i] + bc);
            }
        }
    }
}

// --------- MFMA MLP head: sigmoid(relu(h2@W1+b1)@W2 + b2), fused ----------
__global__ __launch_bounds__(256) void k_mlp_mfma(
        const __hip_bfloat16* __restrict__ h2, const __hip_bfloat16* __restrict__ W1t,
        const float* __restrict__ b1, const float* __restrict__ W2,
        const float* __restrict__ b2, int N,
        void* __restrict__ d_out, const int* __restrict__ flag) {
    __shared__ __hip_bfloat16 hA[64 * AS];
    __shared__ __hip_bfloat16 wB[128 * AS];
    int t = threadIdx.x, rbase = blockIdx.x * 64;
    for (int i = t; i < 2048; i += 256) {
        int c = i >> 4, seg = i & 15;
        ((uint4*)(wB + c * AS))[seg] = ((const uint4*)(W1t + c * 128))[seg];
    }
    for (int i = t; i < 1024; i += 256) {
        int r = i >> 4, seg = i & 15;
        int gr = rbase + r;
        uint4 v = {0u, 0u, 0u, 0u};
        if (gr < N) v = ((const uint4*)(h2 + (size_t)gr * 128))[seg];
        ((uint4*)(hA + r * AS))[seg] = v;
    }
    __syncthreads();
    int wave = t >> 6, lane = t & 63, l16 = lane & 15, kq = lane >> 4;
    f32x4 acc[8];
#pragma unroll
    for (int i = 0; i < 8; ++i) acc[i] = (f32x4){0.f, 0.f, 0.f, 0.f};
#pragma unroll
    for (int ks = 0; ks < 4; ++ks) {
        int kofs = ks * 32 + kq * 8;
        bf16x8 a = *(const bf16x8*)(hA + (wave * 16 + l16) * AS + kofs);
#pragma unroll
        for (int cb = 0; cb < 8; ++cb) {
            bf16x8 b = *(const bf16x8*)(wB + (cb * 16 + l16) * AS + kofs);
            acc[cb] = __builtin_amdgcn_mfma_f32_16x16x32_bf16(a, b, acc[cb], 0, 0, 0);
        }
    }
    float p[4] = {0.f, 0.f, 0.f, 0.f};
#pragma unroll
    for (int cb = 0; cb < 8; ++cb) {
        int c = cb * 16 + l16;
        float bb = b1[c], w = W2[c];
#pragma unroll
        for (int i = 0; i < 4; ++i) p[i] += fmaxf(acc[cb][i] + bb, 0.f) * w;
    }
#pragma unroll
    for (int i = 0; i < 4; ++i) {
        p[i] += __shfl_xor(p[i], 8, 16);
        p[i] += __shfl_xor(p[i], 4, 16);
        p[i] += __shfl_xor(p[i], 2, 16);
        p[i] += __shfl_xor(p[i], 1, 16);
    }
    if (l16 == 0) {
        int isF32 = *flag;
        float bb = b2[0];
#pragma unroll
        for (int i = 0; i < 4; ++i) {
            int r = rbase + wave * 16 + kq * 4 + i;
            if (r < N)
                store_out(d_out, (size_t)r,
                          1.f / (1.f + __expf(-(p[i] + bb))), isF32);
        }
    }
}

// ===== fused GAT edge pipeline: round-11 scalar math + int4 index loads ===
__device__ __forceinline__ float edge_p(unsigned u, float xr0, float xr1,
                                        float a0, float a1) {
    float v0 = lo16(u) + xr0; v0 = fmaxf(v0, NEG_SLOPE * v0);   // leaky, 2 ops
    float v1 = hi16(u) + xr1; v1 = fmaxf(v1, NEG_SLOPE * v1);
    return v0 * a0 + v1 * a1;
}

__global__ __launch_bounds__(256) void k_gat_fused(
        const __hip_bfloat16* __restrict__ xl,
        const __hip_bfloat16* __restrict__ xr,
        const int* __restrict__ rs, const int* __restrict__ cnt,
        const int* __restrict__ srcc, const int* __restrict__ eidx, int N,
        const float* __restrict__ att, const float* __restrict__ bo, int relu,
        float* __restrict__ EX2,
        void* __restrict__ alpha_out, size_t aoff, const int* __restrict__ flag,
        __hip_bfloat16* __restrict__ hout) {
    __shared__ float exsh[4][CAPD * 4];     // per-wave ex cache (4 KB)
    int wv = threadIdx.x >> 6, lane = threadIdx.x & 63;
    int n = blockIdx.x * 4 + wv;
    if (n >= N) return;
    int h = lane >> 4, l16 = lane & 15, c0 = lane * 2;
    unsigned uxr = ((const unsigned*)(xr + (size_t)n * 128))[lane];
    float xr0 = lo16(uxr), xr1 = hi16(uxr);
    float a0 = att[c0], a1 = att[c0 + 1];
    int beg = rs[n];                        // 16B-aligned (padded CSR)
    int end = beg + cnt[n];                 // true extent
    float den = 0.f, acc0 = 0.f, acc1 = 0.f;
    int r = beg;
    for (; r + 8 <= end; r += 8) {                 // 8 edges, 2 int4 index loads
        int4 sa = *(const int4*)(srcc + r);
        int4 sb = *(const int4*)(srcc + r + 4);
        int sv[8] = {sa.x, sa.y, sa.z, sa.w, sb.x, sb.y, sb.z, sb.w};
        unsigned u[8];
#pragma unroll
        for (int j = 0; j < 8; ++j) {
            unsigned s = min((unsigned)sv[j], (unsigned)(N - 1));
            u[j] = ((const unsigned*)(xl + (size_t)s * 128))[lane];
        }
        float p[8];
#pragma unroll
        for (int j = 0; j < 8; ++j) p[j] = edge_p(u[j], xr0, xr1, a0, a1);
#pragma unroll
        for (int st = 1; st < 16; st <<= 1) {
#pragma unroll
            for (int j = 0; j < 8; ++j) p[j] += __shfl_xor(p[j], st, 16);
        }
        float ex[8];
#pragma unroll
        for (int j = 0; j < 8; ++j) ex[j] = __expf(fminf(fmaxf(p[j], -30.f), 30.f));
        if (l16 == 0) {
#pragma unroll
            for (int j = 0; j < 8; ++j) {
                int idx = r + j - beg;
                if (idx < CAPD) exsh[wv][idx * 4 + h] = ex[j];
                else            EX2[(size_t)(r + j) * 4 + h] = ex[j];
            }
        }
#pragma unroll
        for (int j = 0; j < 8; ++j) {
            den  += ex[j];
            acc0 += ex[j] * lo16(u[j]);
            acc1 += ex[j] * hi16(u[j]);
        }
    }
    if (r < end) {                                 // masked tail; padded slack readable
        int4 sa = *(const int4*)(srcc + r);
        int4 sb = *(const int4*)(srcc + r + 4);
        int sv[8] = {sa.x, sa.y, sa.z, sa.w, sb.x, sb.y, sb.z, sb.w};
        unsigned u[8];
#pragma unroll
        for (int j = 0; j < 8; ++j) {
            unsigned s = min((unsigned)sv[j], (unsigned)(N - 1));
            u[j] = ((const unsigned*)(xl + (size_t)s * 128))[lane];
        }
        float p[8];
#pragma unroll
        for (int j = 0; j < 8; ++j) p[j] = edge_p(u[j], xr0, xr1, a0, a1);
#pragma unroll
        for (int st = 1; st < 16; st <<= 1) {
#pragma unroll
            for (int j = 0; j < 8; ++j) p[j] += __shfl_xor(p[j], st, 16);
        }
        float ex[8];
#pragma unroll
        for (int j = 0; j < 8; ++j)
            ex[j] = (r + j < end) ? __expf(fminf(fmaxf(p[j], -30.f), 30.f)) : 0.f;
        if (l16 == 0) {
#pragma unroll
            for (int j = 0; j < 8; ++j) {
                if (r + j < end) {
                    int idx = r + j - beg;
                    if (idx < CAPD) exsh[wv][idx * 4 + h] = ex[j];
                    else            EX2[(size_t)(r + j) * 4 + h] = ex[j];
                }
            }
        }
#pragma unroll
        for (int j = 0; j < 8; ++j) {
            den  += ex[j];
            acc0 += ex[j] * lo16(u[j]);
            acc1 += ex[j] * hi16(u[j]);
        }
    }
    float invn = 1.f / fmaxf(den, 1e-30f);
    float v0 = acc0 * invn + bo[c0], v1 = acc1 * invn + bo[c0 + 1];
    if (relu) { v0 = fmaxf(v0, 0.f); v1 = fmaxf(v1, 0.f); }
    __hip_bfloat16 h0 = f2b(v0), h1 = f2b(v1);
    ushort2 st;
    st.x = *(unsigned short*)&h0;
    st.y = *(unsigned short*)&h1;
    ((ushort2*)(hout + (size_t)n * 128))[lane] = st;
    // alpha outputs: 16 edges in parallel, lane (h,l16) handles (r0+l16, h)
    int isF32 = *flag;
    for (int r0 = beg; r0 < end; r0 += 16) {
        int rr = r0 + l16;
        if (rr < end) {
            int idx = rr - beg;
            float ex = (idx < CAPD) ? exsh[wv][idx * 4 + h]
                                    : EX2[(size_t)rr * 4 + h];
            int e = eidx[rr];
            store_out(alpha_out, aoff + (size_t)e * 4 + h, ex * invn, isF32);
        }
    }
}

extern "C" void kernel_launch(void* const* d_in, const int* in_sizes, int n_in,
                              void* d_out, int out_size, void* d_ws, size_t ws_size,
                              hipStream_t stream) {
    const int* ei = (const int*)d_in[1];
    const int N  = in_sizes[0] / 16;
    const int E  = in_sizes[1] / 2;
    const int ET = E + N;
    const int ETP = ET + 3 * N + 16;         // padded CSR capacity (+slack)
    const int NB = (N + 255) / 256;          // scan blocks

    // ---------------- workspace carve ------------------------------------
    float* P = (float*)d_ws;
    float* encW = P; P += 2048;  float* encb = P; P += 128;
    float* b1l  = P; P += 128;   float* b1r  = P; P += 128;
    float* att1 = P; P += 128;   float* bo1  = P; P += 128;
    float* b2l  = P; P += 128;   float* b2r  = P; P += 128;
    float* att2 = P; P += 128;   float* bo2  = P; P += 128;
    float* mb1  = P; P += 128;   float* mW2  = P; P += 128;
    float* mb2  = P; P += 4;
    int*  FLAG  = (int*)P; P += 4;
    int*  CNT   = (int*)P; P += N;
    int*  RS    = (int*)P; P += N + 1;
    int*  CUR   = (int*)P; P += N;
    int*  BSUM  = (int*)P; P += NB;
    P = (float*)(((uintptr_t)P + 15) & ~(uintptr_t)15);   // 16B align EIDX/SRC
    int*  EIDX  = (int*)P; P += ETP;
    int*  SRC   = (int*)P; P += ETP;
    float* EX2  = P; P += (size_t)ETP * 4;
    P = (float*)(((uintptr_t)P + 15) & ~(uintptr_t)15);   // 16B align
    __hip_bfloat16* W1Lt = (__hip_bfloat16*)P;            // 5 x 128*128 bf16
    __hip_bfloat16* W1Rt = W1Lt + 16384;
    __hip_bfloat16* W2Lt = W1Rt + 16384;
    __hip_bfloat16* W2Rt = W2Lt + 16384;
    __hip_bfloat16* MW1t = W2Rt + 16384;
    __hip_bfloat16* Hb   = MW1t + 16384;                  // N*128 bf16
    __hip_bfloat16* XL   = Hb + (size_t)N * 128;
    __hip_bfloat16* XR   = XL + (size_t)N * 128;

    // ---------------- fused setup (cvt + transpose + CNT zero) ------------
    SetupTab tab;
    const int srcIdx[NCVT] = {4, 5, 7, 9, 10, 11, 13, 15, 16, 17, 19, 20, 21};
    float* dsts[NCVT] = {encW, encb, b1l, b1r, att1, bo1, b2l, b2r, att2, bo2, mb1, mW2, mb2};
    const int ns[NCVT] = {2048, 128, 128, 128, 128, 128, 128, 128, 128, 128, 128, 128, 1};
    int tot = 0;
    for (int i = 0; i < NCVT; ++i) {
        tab.csrc[i] = d_in[srcIdx[i]];
        tab.cdst[i] = dsts[i];
        tab.cn[i] = ns[i];
        tot += ns[i];
    }
    tab.ctotal = tot;
    tab.wsrc[0] = d_in[6];  tab.wdst[0] = W1Lt;
    tab.wsrc[1] = d_in[8];  tab.wdst[1] = W1Rt;
    tab.wsrc[2] = d_in[12]; tab.wdst[2] = W2Lt;
    tab.wsrc[3] = d_in[14]; tab.wdst[3] = W2Rt;
    tab.wsrc[4] = d_in[18]; tab.wdst[4] = MW1t;
    const unsigned short* det = (const unsigned short*)d_in[4];  // enc_W raw
    const int nWt   = 5 * 16384 / 256;     // 320
    const int nCvt  = (tot + 255) / 256;
    k_setup<<<nWt + NB + nCvt, 256, 0, stream>>>(tab, det, FLAG, CNT, N, nWt, NB);

    // ---------------- CSR by dst (parallel scan, padded rows) -------------
    const int etGrid = (ET + 255) / 256;
    k_hist<<<etGrid, 256, 0, stream>>>(ei, E, N, CNT);
    k_scanA<<<NB, 256, 0, stream>>>(CNT, N, RS, BSUM);
    k_scanB<<<1, 1024, 0, stream>>>(BSUM, NB, RS, N);
    k_scanC<<<NB, 256, 0, stream>>>(RS, CUR, BSUM, N);
    k_fill<<<etGrid, 256, 0, stream>>>(ei, E, N, CUR, EIDX, SRC);

    const size_t a1_off = (size_t)N;
    const size_t a2_off = (size_t)N + (size_t)ET * 4;
    const int gGrid = (N + 63) / 64;
    const int fGrid = (N + 3) / 4;

    // ---- GAT layer 1 (encoder fused into the GEMM) ----
    k_gemm2enc_mfma<<<gGrid, 256, 0, stream>>>(d_in[0], encW, encb, FLAG,
                                               W1Lt, b1l, W1Rt, b1r, N, XL, XR);
    k_gat_fused<<<fGrid, 256, 0, stream>>>(XL, XR, RS, CNT, SRC, EIDX, N, att1, bo1, 1,
                                           EX2, d_out, a1_off, FLAG, Hb);

    // ---- GAT layer 2 ----
    k_gemm2_mfma<<<gGrid, 256, 0, stream>>>(Hb, W2Lt, b2l, W2Rt, b2r, N, XL, XR);
    k_gat_fused<<<fGrid, 256, 0, stream>>>(XL, XR, RS, CNT, SRC, EIDX, N, att2, bo2, 0,
                                           EX2, d_out, a2_off, FLAG, Hb);

    k_mlp_mfma<<<gGrid, 256, 0, stream>>>(Hb, MW1t, mb1, mW2, mb2, N, d_out, FLAG);
}